// Round 11
// baseline (209.539 us; speedup 1.0000x reference)
//
#include <hip/hip_runtime.h>
#include <hip/hip_bf16.h>

#define NN 50000
#define NE 800000
#define D 128
#define DOUT 64
#define PAD 64     // slots per node; P(deg>=64) ~ 2e-18 for Poisson(16)
#define BSH 8      // nodes per bucket = 256
#define NBUCK 196  // ceil(50000/256)
#define CAP 4608   // bucket capacity: mean 4096 + 8 sigma
#define CHUNK 4096 // edges per bin_edges block (196 blocks)
#define N8 (NN * D / 8)

typedef __attribute__((ext_vector_type(8))) short short8;
typedef __attribute__((ext_vector_type(4))) float float4v;

// ---------------- bf16 helpers ----------------

__device__ inline unsigned short f2bf(float f) {
    union { float f; unsigned int i; } c; c.f = f;
    unsigned int u = c.i;
    return (unsigned short)((u + 0x7fffu + ((u >> 16) & 1u)) >> 16);  // RNE
}
__device__ inline float bflo(unsigned int u) {
    union { unsigned int i; float f; } c; c.i = u << 16; return c.f;
}
__device__ inline float bfhi(unsigned int u) {
    union { unsigned int i; float f; } c; c.i = u & 0xffff0000u; return c.f;
}

// ---------------- prep: cast x->bf16 + pack all weights + zero gcur (ONE launch) ----

struct PrepArgs {
    const float* W[5];
    unsigned short* P[5];
    int* gcur;
    const float* x;
    unsigned short* xb;
};

__global__ void prep(PrepArgs args) {
    int b = blockIdx.x;
    if (b < 36) {
        int idx = b * 256 + threadIdx.x;   // 0..9215
        const float* W;
        unsigned short* P;
        int COLS, local;
        if (idx < 4 * 2048) {
            int wsel = idx >> 11;
            W = args.W[wsel]; P = args.P[wsel]; COLS = 128; local = idx & 2047;
        } else {
            W = args.W[4]; P = args.P[4]; COLS = 64; local = idx - 4 * 2048;
        }
        int CT = COLS >> 4;
        int lane = local & 63;
        int fi = local >> 6;
        int ct = fi % CT;
        int kstep = fi / CT;
        int krow = kstep * 32 + (lane >> 4) * 8;
        int col = ct * 16 + (lane & 15);
        unsigned short v[8];
#pragma unroll
        for (int j = 0; j < 8; ++j) v[j] = f2bf(W[(size_t)(krow + j) * COLS + col]);
        unsigned int w0 = v[0] | ((unsigned int)v[1] << 16);
        unsigned int w1 = v[2] | ((unsigned int)v[3] << 16);
        unsigned int w2 = v[4] | ((unsigned int)v[5] << 16);
        unsigned int w3 = v[6] | ((unsigned int)v[7] << 16);
        *(uint4*)(P + (size_t)local * 8) = make_uint4(w0, w1, w2, w3);
    } else if (b == 36) {
        if (threadIdx.x < NBUCK) args.gcur[threadIdx.x] = 0;
    } else {
        int stride = (gridDim.x - 37) * 256;
        for (int i = (b - 37) * 256 + threadIdx.x; i < N8; i += stride) {
            const float4* p = (const float4*)args.x + (size_t)i * 2;
            float4 a = p[0], bb = p[1];
            unsigned int w0 = f2bf(a.x) | ((unsigned int)f2bf(a.y) << 16);
            unsigned int w1 = f2bf(a.z) | ((unsigned int)f2bf(a.w) << 16);
            unsigned int w2 = f2bf(bb.x) | ((unsigned int)f2bf(bb.y) << 16);
            unsigned int w3 = f2bf(bb.z) | ((unsigned int)f2bf(bb.w) << 16);
            *(uint4*)(args.xb + (size_t)i * 8) = make_uint4(w0, w1, w2, w3);
        }
    }
}

// ---------------- pass 1: block counting-sort of edges into dst buckets ----------------

__global__ void bin_edges(const int* __restrict__ src, const int* __restrict__ dst,
                          int* __restrict__ gcur, unsigned int* __restrict__ binned, int e) {
    __shared__ int cnt[NBUCK];
    __shared__ int sh[256];
    __shared__ int baseg[NBUCK];
    __shared__ int lcur[NBUCK];
    __shared__ unsigned int buf[CHUNK];
    int tid = threadIdx.x;
    int base = blockIdx.x * CHUNK;
    for (int b = tid; b < NBUCK; b += 256) cnt[b] = 0;
    __syncthreads();
    unsigned int rec[16];
#pragma unroll
    for (int i = 0; i < 16; ++i) {
        int ei = base + i * 256 + tid;
        rec[i] = 0xffffffffu;
        if (ei < e) {
            unsigned int d = (unsigned int)dst[ei];
            unsigned int s = (unsigned int)src[ei];
            rec[i] = (d << 16) | s;
            atomicAdd(&cnt[d >> BSH], 1);
        }
    }
    __syncthreads();
    int v = (tid < NBUCK) ? cnt[tid] : 0;
    sh[tid] = v;
    __syncthreads();
    for (int off = 1; off < 256; off <<= 1) {
        int t = (tid >= off) ? sh[tid - off] : 0;
        __syncthreads();
        sh[tid] += t;
        __syncthreads();
    }
    if (tid < NBUCK) {
        baseg[tid] = atomicAdd(&gcur[tid], cnt[tid]);
        lcur[tid] = sh[tid] - cnt[tid];
    }
    __syncthreads();
    int total = sh[255];
#pragma unroll
    for (int i = 0; i < 16; ++i) {
        if (rec[i] != 0xffffffffu) {
            int b = rec[i] >> 24;
            int pos = atomicAdd(&lcur[b], 1);
            buf[pos] = rec[i];
        }
    }
    __syncthreads();
    for (int j = tid; j < total; j += 256) {
        unsigned int r = buf[j];
        int b = r >> 24;
        int gidx = baseg[b] + (j - (sh[b] - cnt[b]));
        if (gidx < CAP) binned[(size_t)b * CAP + gidx] = r;
    }
}

// ---------------- pass 2: per-bucket scatter, LDS cursors, L2-local writes ----------------

__global__ void scatter_bucket(const unsigned int* __restrict__ binned, const int* __restrict__ gcur,
                               unsigned short* __restrict__ eidx_pad, int* __restrict__ cursor) {
    __shared__ int cur[256];
    int b = blockIdx.x;
    int tid = threadIdx.x;
    if (tid < 256) cur[tid] = 0;
    __syncthreads();
    int count = gcur[b];
    if (count > CAP) count = CAP;
    const unsigned int* seg = binned + (size_t)b * CAP;
    for (int j = tid; j < count; j += 512) {
        unsigned int r = seg[j];
        int dl = (r >> 16) & 255;
        int slot = atomicAdd(&cur[dl], 1);
        if (slot < PAD)
            eidx_pad[((size_t)((b << BSH) + dl)) * PAD + slot] = (unsigned short)(r & 0xffffu);
    }
    __syncthreads();
    if (tid < 256) {
        int node = (b << BSH) + tid;
        if (node < NN) cursor[node] = (cur[tid] < PAD) ? cur[tid] : PAD;
    }
}

// ---------------- fused layer: agg-gather + dual MFMA GEMM [+ fused FC] ----------------
// Block = 32 nodes, 256 threads, __launch_bounds__(256,4) -- the PROVEN register
// budget (VGPR cap 128, compiler uses ~48, no spill). Grid = 1563 blocks -> ~6
// blocks/CU, ~24 waves/CU (2x r10). Gather: 16 groups x 16 lanes, 2 nodes per
// group (halves each wave's serial latency chain vs r10's 4), 8 gathers in
// flight, lane = one 16B column chunk. X (self) operand direct from global.
// FUSEFC: h -> As (LDS only), out = h @ Pfc + bfc (fp32).
// r8/r9 lesson: never tighten launch_bounds below (256,4) -- (512,8)/(256,6)
// both spilled gather buffers to scratch (+16-47 MB FETCH/WRITE).

template <bool FUSEFC>
__global__ __launch_bounds__(256, 4)
void fused_layer(const unsigned short* __restrict__ feat,
                 const int* __restrict__ cursor, const unsigned short* __restrict__ eidx_pad,
                 const unsigned short* __restrict__ Pl, const unsigned short* __restrict__ Pr,
                 const float* __restrict__ bias,
                 const unsigned short* __restrict__ Pfc, const float* __restrict__ bfc,
                 unsigned short* __restrict__ outb, float* __restrict__ outf, int n) {
    __shared__ __align__(16) unsigned short As[32][136];

    int tid = threadIdx.x;
    int row0 = blockIdx.x * 32;

    // gather-aggregate -> As: group g (16 lanes) handles nodes g*2, g*2+1
    {
        int g = tid >> 4;
        int l = tid & 15;
#pragma unroll
        for (int nn = 0; nn < 2; ++nn) {
            int r = g * 2 + nn;
            int node = row0 + r;
            float acc[8] = {0.f, 0.f, 0.f, 0.f, 0.f, 0.f, 0.f, 0.f};
            float di = 1.f;
            if (node < n) {
                int deg = cursor[node];
                di = 1.0f / (float)(deg > 1 ? deg : 1);
                const unsigned short* rowp = eidx_pad + (size_t)node * PAD;
                int p = 0;
                for (; p + 7 < deg; p += 8) {
                    uint4 iv = *(const uint4*)(rowp + p);
                    int s0 = iv.x & 0xffff, s1 = iv.x >> 16;
                    int s2 = iv.y & 0xffff, s3 = iv.y >> 16;
                    int s4 = iv.z & 0xffff, s5 = iv.z >> 16;
                    int s6 = iv.w & 0xffff, s7 = iv.w >> 16;
                    uint4 v0 = *(const uint4*)(feat + (size_t)s0 * D + l * 8);
                    uint4 v1 = *(const uint4*)(feat + (size_t)s1 * D + l * 8);
                    uint4 v2 = *(const uint4*)(feat + (size_t)s2 * D + l * 8);
                    uint4 v3 = *(const uint4*)(feat + (size_t)s3 * D + l * 8);
                    uint4 v4 = *(const uint4*)(feat + (size_t)s4 * D + l * 8);
                    uint4 v5 = *(const uint4*)(feat + (size_t)s5 * D + l * 8);
                    uint4 v6 = *(const uint4*)(feat + (size_t)s6 * D + l * 8);
                    uint4 v7 = *(const uint4*)(feat + (size_t)s7 * D + l * 8);
                    acc[0] += ((bflo(v0.x) + bflo(v1.x)) + (bflo(v2.x) + bflo(v3.x)))
                            + ((bflo(v4.x) + bflo(v5.x)) + (bflo(v6.x) + bflo(v7.x)));
                    acc[1] += ((bfhi(v0.x) + bfhi(v1.x)) + (bfhi(v2.x) + bfhi(v3.x)))
                            + ((bfhi(v4.x) + bfhi(v5.x)) + (bfhi(v6.x) + bfhi(v7.x)));
                    acc[2] += ((bflo(v0.y) + bflo(v1.y)) + (bflo(v2.y) + bflo(v3.y)))
                            + ((bflo(v4.y) + bflo(v5.y)) + (bflo(v6.y) + bflo(v7.y)));
                    acc[3] += ((bfhi(v0.y) + bfhi(v1.y)) + (bfhi(v2.y) + bfhi(v3.y)))
                            + ((bfhi(v4.y) + bfhi(v5.y)) + (bfhi(v6.y) + bfhi(v7.y)));
                    acc[4] += ((bflo(v0.z) + bflo(v1.z)) + (bflo(v2.z) + bflo(v3.z)))
                            + ((bflo(v4.z) + bflo(v5.z)) + (bflo(v6.z) + bflo(v7.z)));
                    acc[5] += ((bfhi(v0.z) + bfhi(v1.z)) + (bfhi(v2.z) + bfhi(v3.z)))
                            + ((bfhi(v4.z) + bfhi(v5.z)) + (bfhi(v6.z) + bfhi(v7.z)));
                    acc[6] += ((bflo(v0.w) + bflo(v1.w)) + (bflo(v2.w) + bflo(v3.w)))
                            + ((bflo(v4.w) + bflo(v5.w)) + (bflo(v6.w) + bflo(v7.w)));
                    acc[7] += ((bfhi(v0.w) + bfhi(v1.w)) + (bfhi(v2.w) + bfhi(v3.w)))
                            + ((bfhi(v4.w) + bfhi(v5.w)) + (bfhi(v6.w) + bfhi(v7.w)));
                }
                if (p + 3 < deg) {
                    uint2 iv = *(const uint2*)(rowp + p);
                    int s0 = iv.x & 0xffff, s1 = iv.x >> 16;
                    int s2 = iv.y & 0xffff, s3 = iv.y >> 16;
                    uint4 v0 = *(const uint4*)(feat + (size_t)s0 * D + l * 8);
                    uint4 v1 = *(const uint4*)(feat + (size_t)s1 * D + l * 8);
                    uint4 v2 = *(const uint4*)(feat + (size_t)s2 * D + l * 8);
                    uint4 v3 = *(const uint4*)(feat + (size_t)s3 * D + l * 8);
                    acc[0] += (bflo(v0.x) + bflo(v1.x)) + (bflo(v2.x) + bflo(v3.x));
                    acc[1] += (bfhi(v0.x) + bfhi(v1.x)) + (bfhi(v2.x) + bfhi(v3.x));
                    acc[2] += (bflo(v0.y) + bflo(v1.y)) + (bflo(v2.y) + bflo(v3.y));
                    acc[3] += (bfhi(v0.y) + bfhi(v1.y)) + (bfhi(v2.y) + bfhi(v3.y));
                    acc[4] += (bflo(v0.z) + bflo(v1.z)) + (bflo(v2.z) + bflo(v3.z));
                    acc[5] += (bfhi(v0.z) + bfhi(v1.z)) + (bfhi(v2.z) + bfhi(v3.z));
                    acc[6] += (bflo(v0.w) + bflo(v1.w)) + (bflo(v2.w) + bflo(v3.w));
                    acc[7] += (bfhi(v0.w) + bfhi(v1.w)) + (bfhi(v2.w) + bfhi(v3.w));
                    p += 4;
                }
                for (; p < deg; ++p) {
                    int s = rowp[p];
                    uint4 v0 = *(const uint4*)(feat + (size_t)s * D + l * 8);
                    acc[0] += bflo(v0.x); acc[1] += bfhi(v0.x);
                    acc[2] += bflo(v0.y); acc[3] += bfhi(v0.y);
                    acc[4] += bflo(v0.z); acc[5] += bfhi(v0.z);
                    acc[6] += bflo(v0.w); acc[7] += bfhi(v0.w);
                }
            }
            unsigned int w0 = f2bf(acc[0] * di) | ((unsigned int)f2bf(acc[1] * di) << 16);
            unsigned int w1 = f2bf(acc[2] * di) | ((unsigned int)f2bf(acc[3] * di) << 16);
            unsigned int w2 = f2bf(acc[4] * di) | ((unsigned int)f2bf(acc[5] * di) << 16);
            unsigned int w3 = f2bf(acc[6] * di) | ((unsigned int)f2bf(acc[7] * di) << 16);
            *(uint4*)&As[r][l * 8] = make_uint4(w0, w1, w2, w3);
        }
    }
    __syncthreads();

    int wave = tid >> 6;           // 0..3
    int lane = tid & 63;
    int m16 = lane & 15;
    int quad = lane >> 4;
    int rt0 = (wave & 1) * 16;     // 2 row tiles of 16
    int ctb = (wave >> 1) * 4;     // 2 col halves x 4 tiles

    float4v acc[4];
#pragma unroll
    for (int c = 0; c < 4; ++c) acc[c] = (float4v){0.f, 0.f, 0.f, 0.f};

    // A-operand pass (aggregated, from LDS)
#pragma unroll
    for (int ks = 0; ks < 4; ++ks) {
        short8 af = *(const short8*)&As[rt0 + m16][ks * 32 + quad * 8];
#pragma unroll
        for (int c = 0; c < 4; ++c) {
            short8 bf = *(const short8*)(Pl + ((size_t)((ks * 8 + ctb + c) * 64 + lane)) * 8);
            acc[c] = __builtin_amdgcn_mfma_f32_16x16x32_bf16(af, bf, acc[c], 0, 0, 0);
        }
    }
    // X-operand pass (self rows, direct from global; L2-hot)
#pragma unroll
    for (int ks = 0; ks < 4; ++ks) {
        int row = row0 + rt0 + m16;
        short8 z = {0, 0, 0, 0, 0, 0, 0, 0};
        short8 xf = (row < n) ? *(const short8*)(feat + (size_t)row * D + ks * 32 + quad * 8) : z;
#pragma unroll
        for (int c = 0; c < 4; ++c) {
            short8 bf = *(const short8*)(Pr + ((size_t)((ks * 8 + ctb + c) * 64 + lane)) * 8);
            acc[c] = __builtin_amdgcn_mfma_f32_16x16x32_bf16(xf, bf, acc[c], 0, 0, 0);
        }
    }

    if (!FUSEFC) {
#pragma unroll
        for (int c = 0; c < 4; ++c) {
            int col = (ctb + c) * 16 + m16;
            float bv = bias[col];
#pragma unroll
            for (int i = 0; i < 4; ++i) {
                int row = row0 + rt0 + quad * 4 + i;
                if (row < n)
                    outb[(size_t)row * D + col] = f2bf(fmaxf(acc[c][i] + bv, 0.f));
            }
        }
    } else {
        __syncthreads();
#pragma unroll
        for (int c = 0; c < 4; ++c) {
            int col = (ctb + c) * 16 + m16;
            float bv = bias[col];
#pragma unroll
            for (int i = 0; i < 4; ++i) {
                int row = rt0 + quad * 4 + i;
                As[row][col] = f2bf(fmaxf(acc[c][i] + bv, 0.f));
            }
        }
        __syncthreads();

        int ctbF = (wave >> 1) * 2;   // col tiles {0,1} or {2,3}
        float4v acc2[2];
#pragma unroll
        for (int c = 0; c < 2; ++c) acc2[c] = (float4v){0.f, 0.f, 0.f, 0.f};
#pragma unroll
        for (int ks = 0; ks < 4; ++ks) {
            short8 hf = *(const short8*)&As[rt0 + m16][ks * 32 + quad * 8];
#pragma unroll
            for (int c = 0; c < 2; ++c) {
                short8 bf = *(const short8*)(Pfc + ((size_t)((ks * 4 + ctbF + c) * 64 + lane)) * 8);
                acc2[c] = __builtin_amdgcn_mfma_f32_16x16x32_bf16(hf, bf, acc2[c], 0, 0, 0);
            }
        }
#pragma unroll
        for (int c = 0; c < 2; ++c) {
            int col = (ctbF + c) * 16 + m16;
            float bv = bfc[col];
#pragma unroll
            for (int i = 0; i < 4; ++i) {
                int row = row0 + rt0 + quad * 4 + i;
                if (row < n)
                    outf[(size_t)row * DOUT + col] = acc2[c][i] + bv;
            }
        }
    }
}

// ---------------- launch ----------------

extern "C" void kernel_launch(void* const* d_in, const int* in_sizes, int n_in,
                              void* d_out, int out_size, void* d_ws, size_t ws_size,
                              hipStream_t stream) {
    const float* x   = (const float*)d_in[0];
    const int*   ei  = (const int*)d_in[1];
    const float* Wl0 = (const float*)d_in[2];
    const float* Wr0 = (const float*)d_in[3];
    const float* b0  = (const float*)d_in[4];
    const float* Wl1 = (const float*)d_in[5];
    const float* Wr1 = (const float*)d_in[6];
    const float* b1  = (const float*)d_in[7];
    const float* Wfc = (const float*)d_in[8];
    const float* bfc = (const float*)d_in[9];
    float* out = (float*)d_out;

    const int* src = ei;
    const int* dst = ei + NE;

    char* p = (char*)d_ws;
    auto carve = [&](size_t bytes) {
        char* q = p;
        p += (bytes + 255) & ~(size_t)255;
        return q;
    };
    int*            cursor   = (int*)carve(NN * sizeof(int));
    int*            gcur     = (int*)carve(NBUCK * sizeof(int));
    unsigned int*   binned   = (unsigned int*)carve((size_t)NBUCK * CAP * 4);
    unsigned short* eidx_pad = (unsigned short*)carve((size_t)NN * PAD * 2);
    unsigned short* xb   = (unsigned short*)carve((size_t)NN * D * 2);
    unsigned short* h0b  = (unsigned short*)carve((size_t)NN * D * 2);
    unsigned short* Wl0p = (unsigned short*)carve(D * D * 2);
    unsigned short* Wr0p = (unsigned short*)carve(D * D * 2);
    unsigned short* Wl1p = (unsigned short*)carve(D * D * 2);
    unsigned short* Wr1p = (unsigned short*)carve(D * D * 2);
    unsigned short* Wfcp = (unsigned short*)carve(D * DOUT * 2);

    PrepArgs pa;
    pa.W[0] = Wl0; pa.W[1] = Wr0; pa.W[2] = Wl1; pa.W[3] = Wr1; pa.W[4] = Wfc;
    pa.P[0] = Wl0p; pa.P[1] = Wr0p; pa.P[2] = Wl1p; pa.P[3] = Wr1p; pa.P[4] = Wfcp;
    pa.gcur = gcur;
    pa.x = x; pa.xb = xb;
    prep<<<256, 256, 0, stream>>>(pa);

    const int BINB = (NE + CHUNK - 1) / CHUNK;   // 196
    bin_edges<<<BINB, 256, 0, stream>>>(src, dst, gcur, binned, NE);
    scatter_bucket<<<NBUCK, 512, 0, stream>>>(binned, gcur, eidx_pad, cursor);

    const int GB = (NN + 31) / 32;   // 1563 blocks -> ~6 blocks/CU

    // layer 0: h0 = relu(agg(xb)@Wl0 + xb@Wr0 + b0)
    fused_layer<false><<<GB, 256, 0, stream>>>(xb, cursor, eidx_pad, Wl0p, Wr0p, b0,
                                               nullptr, nullptr, h0b, nullptr, NN);
    // layer 1 + FC: out = (relu(agg(h0)@Wl1 + h0@Wr1 + b1)) @ Wfc + bfc
    fused_layer<true><<<GB, 256, 0, stream>>>(h0b, cursor, eidx_pad, Wl1p, Wr1p, b1,
                                              Wfcp, bfc, nullptr, out, NN);
}

// Round 12
// 188.975 us; speedup vs baseline: 1.1088x; 1.1088x over previous
//
#include <hip/hip_runtime.h>
#include <hip/hip_bf16.h>

#define NN 50000
#define NE 800000
#define D 128
#define DOUT 64
#define PAD 64     // slots per node; P(deg>=64) ~ 2e-18 for Poisson(16)
#define BSH 8      // nodes per bucket = 256
#define NBUCK 196  // ceil(50000/256)
#define CAP 4608   // bucket capacity: mean 4096 + 8 sigma
#define CHUNK 4096 // edges per bin_edges block (196 blocks)
#define N8 (NN * D / 8)

typedef __attribute__((ext_vector_type(8))) short short8;
typedef __attribute__((ext_vector_type(4))) float float4v;

// ---------------- bf16 helpers ----------------

__device__ inline unsigned short f2bf(float f) {
    union { float f; unsigned int i; } c; c.f = f;
    unsigned int u = c.i;
    return (unsigned short)((u + 0x7fffu + ((u >> 16) & 1u)) >> 16);  // RNE
}
__device__ inline float bflo(unsigned int u) {
    union { unsigned int i; float f; } c; c.i = u << 16; return c.f;
}
__device__ inline float bfhi(unsigned int u) {
    union { unsigned int i; float f; } c; c.i = u & 0xffff0000u; return c.f;
}

// ---------------- prep: cast x->bf16 + pack weights + zero gcur/zrow (ONE launch) ----

struct PrepArgs {
    const float* W[5];
    unsigned short* P[5];
    int* gcur;
    const float* x;
    unsigned short* xb;
    unsigned short* zrow;   // 256B zero row for predicated gathers
};

__global__ void prep(PrepArgs args) {
    int b = blockIdx.x;
    if (b < 36) {
        int idx = b * 256 + threadIdx.x;   // 0..9215
        const float* W;
        unsigned short* P;
        int COLS, local;
        if (idx < 4 * 2048) {
            int wsel = idx >> 11;
            W = args.W[wsel]; P = args.P[wsel]; COLS = 128; local = idx & 2047;
        } else {
            W = args.W[4]; P = args.P[4]; COLS = 64; local = idx - 4 * 2048;
        }
        int CT = COLS >> 4;
        int lane = local & 63;
        int fi = local >> 6;
        int ct = fi % CT;
        int kstep = fi / CT;
        int krow = kstep * 32 + (lane >> 4) * 8;
        int col = ct * 16 + (lane & 15);
        unsigned short v[8];
#pragma unroll
        for (int j = 0; j < 8; ++j) v[j] = f2bf(W[(size_t)(krow + j) * COLS + col]);
        unsigned int w0 = v[0] | ((unsigned int)v[1] << 16);
        unsigned int w1 = v[2] | ((unsigned int)v[3] << 16);
        unsigned int w2 = v[4] | ((unsigned int)v[5] << 16);
        unsigned int w3 = v[6] | ((unsigned int)v[7] << 16);
        *(uint4*)(P + (size_t)local * 8) = make_uint4(w0, w1, w2, w3);
    } else if (b == 36) {
        if (threadIdx.x < NBUCK) args.gcur[threadIdx.x] = 0;
        if (threadIdx.x >= 224 && threadIdx.x < 240)   // 16 x uint4 = 256B zero row
            *(uint4*)(args.zrow + (size_t)(threadIdx.x - 224) * 8) = make_uint4(0, 0, 0, 0);
    } else {
        int stride = (gridDim.x - 37) * 256;
        for (int i = (b - 37) * 256 + threadIdx.x; i < N8; i += stride) {
            const float4* p = (const float4*)args.x + (size_t)i * 2;
            float4 a = p[0], bb = p[1];
            unsigned int w0 = f2bf(a.x) | ((unsigned int)f2bf(a.y) << 16);
            unsigned int w1 = f2bf(a.z) | ((unsigned int)f2bf(a.w) << 16);
            unsigned int w2 = f2bf(bb.x) | ((unsigned int)f2bf(bb.y) << 16);
            unsigned int w3 = f2bf(bb.z) | ((unsigned int)f2bf(bb.w) << 16);
            *(uint4*)(args.xb + (size_t)i * 8) = make_uint4(w0, w1, w2, w3);
        }
    }
}

// ---------------- pass 1: block counting-sort of edges into dst buckets ----------------

__global__ void bin_edges(const int* __restrict__ src, const int* __restrict__ dst,
                          int* __restrict__ gcur, unsigned int* __restrict__ binned, int e) {
    __shared__ int cnt[NBUCK];
    __shared__ int sh[256];
    __shared__ int baseg[NBUCK];
    __shared__ int lcur[NBUCK];
    __shared__ unsigned int buf[CHUNK];
    int tid = threadIdx.x;
    int base = blockIdx.x * CHUNK;
    for (int b = tid; b < NBUCK; b += 256) cnt[b] = 0;
    __syncthreads();
    unsigned int rec[16];
#pragma unroll
    for (int i = 0; i < 16; ++i) {
        int ei = base + i * 256 + tid;
        rec[i] = 0xffffffffu;
        if (ei < e) {
            unsigned int d = (unsigned int)dst[ei];
            unsigned int s = (unsigned int)src[ei];
            rec[i] = (d << 16) | s;
            atomicAdd(&cnt[d >> BSH], 1);
        }
    }
    __syncthreads();
    int v = (tid < NBUCK) ? cnt[tid] : 0;
    sh[tid] = v;
    __syncthreads();
    for (int off = 1; off < 256; off <<= 1) {
        int t = (tid >= off) ? sh[tid - off] : 0;
        __syncthreads();
        sh[tid] += t;
        __syncthreads();
    }
    if (tid < NBUCK) {
        baseg[tid] = atomicAdd(&gcur[tid], cnt[tid]);
        lcur[tid] = sh[tid] - cnt[tid];
    }
    __syncthreads();
    int total = sh[255];
#pragma unroll
    for (int i = 0; i < 16; ++i) {
        if (rec[i] != 0xffffffffu) {
            int b = rec[i] >> 24;
            int pos = atomicAdd(&lcur[b], 1);
            buf[pos] = rec[i];
        }
    }
    __syncthreads();
    for (int j = tid; j < total; j += 256) {
        unsigned int r = buf[j];
        int b = r >> 24;
        int gidx = baseg[b] + (j - (sh[b] - cnt[b]));
        if (gidx < CAP) binned[(size_t)b * CAP + gidx] = r;
    }
}

// ---------------- pass 2: per-bucket scatter, LDS cursors, L2-local writes ----------------

__global__ void scatter_bucket(const unsigned int* __restrict__ binned, const int* __restrict__ gcur,
                               unsigned short* __restrict__ eidx_pad, int* __restrict__ cursor) {
    __shared__ int cur[256];
    int b = blockIdx.x;
    int tid = threadIdx.x;
    if (tid < 256) cur[tid] = 0;
    __syncthreads();
    int count = gcur[b];
    if (count > CAP) count = CAP;
    const unsigned int* seg = binned + (size_t)b * CAP;
    for (int j = tid; j < count; j += 512) {
        unsigned int r = seg[j];
        int dl = (r >> 16) & 255;
        int slot = atomicAdd(&cur[dl], 1);
        if (slot < PAD)
            eidx_pad[((size_t)((b << BSH) + dl)) * PAD + slot] = (unsigned short)(r & 0xffffu);
    }
    __syncthreads();
    if (tid < 256) {
        int node = (b << BSH) + tid;
        if (node < NN) cursor[node] = (cur[tid] < PAD) ? cur[tid] : PAD;
    }
}

// ---------------- fused layer: agg-gather + dual MFMA GEMM [+ fused FC] ----------------
// r10 shape (proven best: 64-node tile, 256 thr, (256,4), 782 blocks = 3/CU,
// 12 waves/CU). Occupancy lever exhausted: r11 measured 24 waves/CU -> BW
// DROPS 2.1->1.93 TB/s (L2 contention); r8/r9 tighter bounds -> scratch spill.
// NEW vs r10: latency-pipelined gather. Per node: both id-uint4s issued at
// once, then 16 predicated gathers (invalid slots -> zrow, exact 0.0 added) --
// per-node chain ~2 latency rounds vs ~3.5; tail = predicated 8-batches, no
// scalar chains. Costs ~3.6 wasted (L2-hit) gathers/node + ~64 VGPR of
// in-flight buffers (cap 128 at (256,4): no spill).

template <bool FUSEFC>
__global__ __launch_bounds__(256, 4)
void fused_layer(const unsigned short* __restrict__ feat,
                 const int* __restrict__ cursor, const unsigned short* __restrict__ eidx_pad,
                 const unsigned short* __restrict__ zrow,
                 const unsigned short* __restrict__ Pl, const unsigned short* __restrict__ Pr,
                 const float* __restrict__ bias,
                 const unsigned short* __restrict__ Pfc, const float* __restrict__ bfc,
                 unsigned short* __restrict__ outb, float* __restrict__ outf, int n) {
    __shared__ __align__(16) unsigned short As[64][136];

    int tid = threadIdx.x;
    int row0 = blockIdx.x * 64;

    // gather-aggregate -> As: group g (16 lanes) handles nodes g*4..g*4+3
    {
        int g = tid >> 4;
        int l = tid & 15;
#pragma unroll
        for (int nn = 0; nn < 4; ++nn) {
            int r = g * 4 + nn;
            int node = row0 + r;
            float acc[8] = {0.f, 0.f, 0.f, 0.f, 0.f, 0.f, 0.f, 0.f};
            float di = 1.f;
            if (node < n) {
                int deg = cursor[node];
                di = 1.0f / (float)(deg > 1 ? deg : 1);
                const unsigned short* rowp = eidx_pad + (size_t)node * PAD;
                // ---- first 16 slots: both id loads + 16 predicated gathers in flight ----
                uint4 iva = *(const uint4*)(rowp);
                uint4 ivb = *(const uint4*)(rowp + 8);
                int id[16];
                id[0] = iva.x & 0xffff;  id[1] = iva.x >> 16;
                id[2] = iva.y & 0xffff;  id[3] = iva.y >> 16;
                id[4] = iva.z & 0xffff;  id[5] = iva.z >> 16;
                id[6] = iva.w & 0xffff;  id[7] = iva.w >> 16;
                id[8] = ivb.x & 0xffff;  id[9] = ivb.x >> 16;
                id[10] = ivb.y & 0xffff; id[11] = ivb.y >> 16;
                id[12] = ivb.z & 0xffff; id[13] = ivb.z >> 16;
                id[14] = ivb.w & 0xffff; id[15] = ivb.w >> 16;
                uint4 v[16];
#pragma unroll
                for (int k = 0; k < 16; ++k) {
                    const unsigned short* sp = (k < deg) ? (feat + (size_t)id[k] * D) : zrow;
                    v[k] = *(const uint4*)(sp + l * 8);
                }
#pragma unroll
                for (int k = 0; k < 16; ++k) {
                    acc[0] += bflo(v[k].x); acc[1] += bfhi(v[k].x);
                    acc[2] += bflo(v[k].y); acc[3] += bfhi(v[k].y);
                    acc[4] += bflo(v[k].z); acc[5] += bfhi(v[k].z);
                    acc[6] += bflo(v[k].w); acc[7] += bfhi(v[k].w);
                }
                // ---- tail: predicated batches of 8 (P(deg>16) ~ 0.47) ----
                int p = 16;
                while (p < deg) {
                    uint4 iv = *(const uint4*)(rowp + p);
                    int jd[8];
                    jd[0] = iv.x & 0xffff; jd[1] = iv.x >> 16;
                    jd[2] = iv.y & 0xffff; jd[3] = iv.y >> 16;
                    jd[4] = iv.z & 0xffff; jd[5] = iv.z >> 16;
                    jd[6] = iv.w & 0xffff; jd[7] = iv.w >> 16;
                    uint4 w[8];
#pragma unroll
                    for (int k = 0; k < 8; ++k) {
                        const unsigned short* sp = (p + k < deg) ? (feat + (size_t)jd[k] * D) : zrow;
                        w[k] = *(const uint4*)(sp + l * 8);
                    }
#pragma unroll
                    for (int k = 0; k < 8; ++k) {
                        acc[0] += bflo(w[k].x); acc[1] += bfhi(w[k].x);
                        acc[2] += bflo(w[k].y); acc[3] += bfhi(w[k].y);
                        acc[4] += bflo(w[k].z); acc[5] += bfhi(w[k].z);
                        acc[6] += bflo(w[k].w); acc[7] += bfhi(w[k].w);
                    }
                    p += 8;
                }
            }
            unsigned int w0 = f2bf(acc[0] * di) | ((unsigned int)f2bf(acc[1] * di) << 16);
            unsigned int w1 = f2bf(acc[2] * di) | ((unsigned int)f2bf(acc[3] * di) << 16);
            unsigned int w2 = f2bf(acc[4] * di) | ((unsigned int)f2bf(acc[5] * di) << 16);
            unsigned int w3 = f2bf(acc[6] * di) | ((unsigned int)f2bf(acc[7] * di) << 16);
            *(uint4*)&As[r][l * 8] = make_uint4(w0, w1, w2, w3);
        }
    }
    __syncthreads();

    int wave = tid >> 6;
    int lane = tid & 63;
    int m16 = lane & 15;
    int quad = lane >> 4;
    int rt0 = (wave & 1) * 32;
    int ctb = (wave >> 1) * 4;

    float4v acc[2][4];
#pragma unroll
    for (int t = 0; t < 2; ++t)
#pragma unroll
        for (int c = 0; c < 4; ++c) acc[t][c] = (float4v){0.f, 0.f, 0.f, 0.f};

    // A-operand pass (aggregated, from LDS)
#pragma unroll
    for (int ks = 0; ks < 4; ++ks) {
        short8 af[2];
#pragma unroll
        for (int t = 0; t < 2; ++t)
            af[t] = *(const short8*)&As[rt0 + t * 16 + m16][ks * 32 + quad * 8];
#pragma unroll
        for (int c = 0; c < 4; ++c) {
            short8 bf = *(const short8*)(Pl + ((size_t)((ks * 8 + ctb + c) * 64 + lane)) * 8);
#pragma unroll
            for (int t = 0; t < 2; ++t)
                acc[t][c] = __builtin_amdgcn_mfma_f32_16x16x32_bf16(af[t], bf, acc[t][c], 0, 0, 0);
        }
    }
    // X-operand pass (self rows, direct from global; L2-hot)
#pragma unroll
    for (int ks = 0; ks < 4; ++ks) {
        short8 xf[2];
#pragma unroll
        for (int t = 0; t < 2; ++t) {
            int row = row0 + rt0 + t * 16 + m16;
            short8 z = {0, 0, 0, 0, 0, 0, 0, 0};
            xf[t] = (row < n) ? *(const short8*)(feat + (size_t)row * D + ks * 32 + quad * 8) : z;
        }
#pragma unroll
        for (int c = 0; c < 4; ++c) {
            short8 bf = *(const short8*)(Pr + ((size_t)((ks * 8 + ctb + c) * 64 + lane)) * 8);
#pragma unroll
            for (int t = 0; t < 2; ++t)
                acc[t][c] = __builtin_amdgcn_mfma_f32_16x16x32_bf16(xf[t], bf, acc[t][c], 0, 0, 0);
        }
    }

    if (!FUSEFC) {
#pragma unroll
        for (int t = 0; t < 2; ++t) {
#pragma unroll
            for (int c = 0; c < 4; ++c) {
                int col = (ctb + c) * 16 + m16;
                float bv = bias[col];
#pragma unroll
                for (int i = 0; i < 4; ++i) {
                    int row = row0 + rt0 + t * 16 + quad * 4 + i;
                    if (row < n)
                        outb[(size_t)row * D + col] = f2bf(fmaxf(acc[t][c][i] + bv, 0.f));
                }
            }
        }
    } else {
        __syncthreads();
#pragma unroll
        for (int t = 0; t < 2; ++t) {
#pragma unroll
            for (int c = 0; c < 4; ++c) {
                int col = (ctb + c) * 16 + m16;
                float bv = bias[col];
#pragma unroll
                for (int i = 0; i < 4; ++i) {
                    int row = rt0 + t * 16 + quad * 4 + i;
                    As[row][col] = f2bf(fmaxf(acc[t][c][i] + bv, 0.f));
                }
            }
        }
        __syncthreads();

        int ctbF = (wave >> 1) * 2;
        float4v acc2[2][2];
#pragma unroll
        for (int t = 0; t < 2; ++t)
#pragma unroll
            for (int c = 0; c < 2; ++c) acc2[t][c] = (float4v){0.f, 0.f, 0.f, 0.f};
#pragma unroll
        for (int ks = 0; ks < 4; ++ks) {
            short8 hf[2];
#pragma unroll
            for (int t = 0; t < 2; ++t)
                hf[t] = *(const short8*)&As[rt0 + t * 16 + m16][ks * 32 + quad * 8];
#pragma unroll
            for (int c = 0; c < 2; ++c) {
                short8 bf = *(const short8*)(Pfc + ((size_t)((ks * 4 + ctbF + c) * 64 + lane)) * 8);
#pragma unroll
                for (int t = 0; t < 2; ++t)
                    acc2[t][c] = __builtin_amdgcn_mfma_f32_16x16x32_bf16(hf[t], bf, acc2[t][c], 0, 0, 0);
            }
        }
#pragma unroll
        for (int t = 0; t < 2; ++t) {
#pragma unroll
            for (int c = 0; c < 2; ++c) {
                int col = (ctbF + c) * 16 + m16;
                float bv = bfc[col];
#pragma unroll
                for (int i = 0; i < 4; ++i) {
                    int row = row0 + rt0 + t * 16 + quad * 4 + i;
                    if (row < n)
                        outf[(size_t)row * DOUT + col] = acc2[t][c][i] + bv;
                }
            }
        }
    }
}

// ---------------- launch ----------------

extern "C" void kernel_launch(void* const* d_in, const int* in_sizes, int n_in,
                              void* d_out, int out_size, void* d_ws, size_t ws_size,
                              hipStream_t stream) {
    const float* x   = (const float*)d_in[0];
    const int*   ei  = (const int*)d_in[1];
    const float* Wl0 = (const float*)d_in[2];
    const float* Wr0 = (const float*)d_in[3];
    const float* b0  = (const float*)d_in[4];
    const float* Wl1 = (const float*)d_in[5];
    const float* Wr1 = (const float*)d_in[6];
    const float* b1  = (const float*)d_in[7];
    const float* Wfc = (const float*)d_in[8];
    const float* bfc = (const float*)d_in[9];
    float* out = (float*)d_out;

    const int* src = ei;
    const int* dst = ei + NE;

    char* p = (char*)d_ws;
    auto carve = [&](size_t bytes) {
        char* q = p;
        p += (bytes + 255) & ~(size_t)255;
        return q;
    };
    int*            cursor   = (int*)carve(NN * sizeof(int));
    int*            gcur     = (int*)carve(NBUCK * sizeof(int));
    unsigned short* zrow     = (unsigned short*)carve(256);
    unsigned int*   binned   = (unsigned int*)carve((size_t)NBUCK * CAP * 4);
    unsigned short* eidx_pad = (unsigned short*)carve((size_t)NN * PAD * 2);
    unsigned short* xb   = (unsigned short*)carve((size_t)NN * D * 2);
    unsigned short* h0b  = (unsigned short*)carve((size_t)NN * D * 2);
    unsigned short* Wl0p = (unsigned short*)carve(D * D * 2);
    unsigned short* Wr0p = (unsigned short*)carve(D * D * 2);
    unsigned short* Wl1p = (unsigned short*)carve(D * D * 2);
    unsigned short* Wr1p = (unsigned short*)carve(D * D * 2);
    unsigned short* Wfcp = (unsigned short*)carve(D * DOUT * 2);

    PrepArgs pa;
    pa.W[0] = Wl0; pa.W[1] = Wr0; pa.W[2] = Wl1; pa.W[3] = Wr1; pa.W[4] = Wfc;
    pa.P[0] = Wl0p; pa.P[1] = Wr0p; pa.P[2] = Wl1p; pa.P[3] = Wr1p; pa.P[4] = Wfcp;
    pa.gcur = gcur;
    pa.x = x; pa.xb = xb;
    pa.zrow = zrow;
    prep<<<256, 256, 0, stream>>>(pa);

    const int BINB = (NE + CHUNK - 1) / CHUNK;   // 196
    bin_edges<<<BINB, 256, 0, stream>>>(src, dst, gcur, binned, NE);
    scatter_bucket<<<NBUCK, 512, 0, stream>>>(binned, gcur, eidx_pad, cursor);

    const int GB = (NN + 63) / 64;   // 782

    // layer 0: h0 = relu(agg(xb)@Wl0 + xb@Wr0 + b0)
    fused_layer<false><<<GB, 256, 0, stream>>>(xb, cursor, eidx_pad, zrow, Wl0p, Wr0p, b0,
                                               nullptr, nullptr, h0b, nullptr, NN);
    // layer 1 + FC: out = (relu(agg(h0)@Wl1 + h0@Wr1 + b1)) @ Wfc + bfc
    fused_layer<true><<<GB, 256, 0, stream>>>(h0b, cursor, eidx_pad, zrow, Wl1p, Wr1p, b1,
                                              Wfcp, bfc, nullptr, out, NN);
}

// Round 13
// 186.954 us; speedup vs baseline: 1.1208x; 1.0108x over previous
//
#include <hip/hip_runtime.h>
#include <hip/hip_bf16.h>

#define NN 50000
#define NE 800000
#define D 128
#define DOUT 64
#define PAD 64     // slots per node; P(deg>=64) ~ 2e-18 for Poisson(16)
#define BSH 8      // nodes per bucket = 256
#define NBUCK 196  // ceil(50000/256)
#define CAP 4608   // bucket capacity: mean 4096 + 8 sigma
#define CHUNK 4096 // edges per bin_edges block (196 blocks)
#define N8 (NN * D / 8)

typedef __attribute__((ext_vector_type(8))) short short8;
typedef __attribute__((ext_vector_type(4))) float float4v;

// ---------------- bf16 helpers ----------------

__device__ inline unsigned short f2bf(float f) {
    union { float f; unsigned int i; } c; c.f = f;
    unsigned int u = c.i;
    return (unsigned short)((u + 0x7fffu + ((u >> 16) & 1u)) >> 16);  // RNE
}
__device__ inline float bflo(unsigned int u) {
    union { unsigned int i; float f; } c; c.i = u << 16; return c.f;
}
__device__ inline float bfhi(unsigned int u) {
    union { unsigned int i; float f; } c; c.i = u & 0xffff0000u; return c.f;
}

// ---------------- prep: cast x->bf16 + pack weights + zero gcur/zrow (ONE launch) ----

struct PrepArgs {
    const float* W[5];
    unsigned short* P[5];
    int* gcur;
    const float* x;
    unsigned short* xb;
    unsigned short* zrow;   // 256B zero row for predicated gathers
};

__global__ void prep(PrepArgs args) {
    int b = blockIdx.x;
    if (b < 36) {
        int idx = b * 256 + threadIdx.x;   // 0..9215
        const float* W;
        unsigned short* P;
        int COLS, local;
        if (idx < 4 * 2048) {
            int wsel = idx >> 11;
            W = args.W[wsel]; P = args.P[wsel]; COLS = 128; local = idx & 2047;
        } else {
            W = args.W[4]; P = args.P[4]; COLS = 64; local = idx - 4 * 2048;
        }
        int CT = COLS >> 4;
        int lane = local & 63;
        int fi = local >> 6;
        int ct = fi % CT;
        int kstep = fi / CT;
        int krow = kstep * 32 + (lane >> 4) * 8;
        int col = ct * 16 + (lane & 15);
        unsigned short v[8];
#pragma unroll
        for (int j = 0; j < 8; ++j) v[j] = f2bf(W[(size_t)(krow + j) * COLS + col]);
        unsigned int w0 = v[0] | ((unsigned int)v[1] << 16);
        unsigned int w1 = v[2] | ((unsigned int)v[3] << 16);
        unsigned int w2 = v[4] | ((unsigned int)v[5] << 16);
        unsigned int w3 = v[6] | ((unsigned int)v[7] << 16);
        *(uint4*)(P + (size_t)local * 8) = make_uint4(w0, w1, w2, w3);
    } else if (b == 36) {
        if (threadIdx.x < NBUCK) args.gcur[threadIdx.x] = 0;
        if (threadIdx.x >= 224 && threadIdx.x < 240)   // 16 x uint4 = 256B zero row
            *(uint4*)(args.zrow + (size_t)(threadIdx.x - 224) * 8) = make_uint4(0, 0, 0, 0);
    } else {
        int stride = (gridDim.x - 37) * 256;
        for (int i = (b - 37) * 256 + threadIdx.x; i < N8; i += stride) {
            const float4* p = (const float4*)args.x + (size_t)i * 2;
            float4 a = p[0], bb = p[1];
            unsigned int w0 = f2bf(a.x) | ((unsigned int)f2bf(a.y) << 16);
            unsigned int w1 = f2bf(a.z) | ((unsigned int)f2bf(a.w) << 16);
            unsigned int w2 = f2bf(bb.x) | ((unsigned int)f2bf(bb.y) << 16);
            unsigned int w3 = f2bf(bb.z) | ((unsigned int)f2bf(bb.w) << 16);
            *(uint4*)(args.xb + (size_t)i * 8) = make_uint4(w0, w1, w2, w3);
        }
    }
}

// ---------------- pass 1: block counting-sort of edges into dst buckets ----------------

__global__ void bin_edges(const int* __restrict__ src, const int* __restrict__ dst,
                          int* __restrict__ gcur, unsigned int* __restrict__ binned, int e) {
    __shared__ int cnt[NBUCK];
    __shared__ int sh[256];
    __shared__ int baseg[NBUCK];
    __shared__ int lcur[NBUCK];
    __shared__ unsigned int buf[CHUNK];
    int tid = threadIdx.x;
    int base = blockIdx.x * CHUNK;
    for (int b = tid; b < NBUCK; b += 256) cnt[b] = 0;
    __syncthreads();
    unsigned int rec[16];
#pragma unroll
    for (int i = 0; i < 16; ++i) {
        int ei = base + i * 256 + tid;
        rec[i] = 0xffffffffu;
        if (ei < e) {
            unsigned int d = (unsigned int)dst[ei];
            unsigned int s = (unsigned int)src[ei];
            rec[i] = (d << 16) | s;
            atomicAdd(&cnt[d >> BSH], 1);
        }
    }
    __syncthreads();
    int v = (tid < NBUCK) ? cnt[tid] : 0;
    sh[tid] = v;
    __syncthreads();
    for (int off = 1; off < 256; off <<= 1) {
        int t = (tid >= off) ? sh[tid - off] : 0;
        __syncthreads();
        sh[tid] += t;
        __syncthreads();
    }
    if (tid < NBUCK) {
        baseg[tid] = atomicAdd(&gcur[tid], cnt[tid]);
        lcur[tid] = sh[tid] - cnt[tid];
    }
    __syncthreads();
    int total = sh[255];
#pragma unroll
    for (int i = 0; i < 16; ++i) {
        if (rec[i] != 0xffffffffu) {
            int b = rec[i] >> 24;
            int pos = atomicAdd(&lcur[b], 1);
            buf[pos] = rec[i];
        }
    }
    __syncthreads();
    for (int j = tid; j < total; j += 256) {
        unsigned int r = buf[j];
        int b = r >> 24;
        int gidx = baseg[b] + (j - (sh[b] - cnt[b]));
        if (gidx < CAP) binned[(size_t)b * CAP + gidx] = r;
    }
}

// ---------------- pass 2: per-bucket scatter, LDS cursors, L2-local writes ----------------

__global__ void scatter_bucket(const unsigned int* __restrict__ binned, const int* __restrict__ gcur,
                               unsigned short* __restrict__ eidx_pad, int* __restrict__ cursor) {
    __shared__ int cur[256];
    int b = blockIdx.x;
    int tid = threadIdx.x;
    if (tid < 256) cur[tid] = 0;
    __syncthreads();
    int count = gcur[b];
    if (count > CAP) count = CAP;
    const unsigned int* seg = binned + (size_t)b * CAP;
    for (int j = tid; j < count; j += 512) {
        unsigned int r = seg[j];
        int dl = (r >> 16) & 255;
        int slot = atomicAdd(&cur[dl], 1);
        if (slot < PAD)
            eidx_pad[((size_t)((b << BSH) + dl)) * PAD + slot] = (unsigned short)(r & 0xffffu);
    }
    __syncthreads();
    if (tid < 256) {
        int node = (b << BSH) + tid;
        if (node < NN) cursor[node] = (cur[tid] < PAD) ? cur[tid] : PAD;
    }
}

// ---------------- fused layer: agg-gather + dual MFMA GEMM [+ fused FC] ----------------
// r12 + two pipeline deepenings:
// (1) id prefetch across nodes: a group's 4 nodes have CONTIGUOUS eidx_pad rows;
//     node nn+1's id-uint4s issue while node nn's 16 gathers are in flight ->
//     per-node chain ~1 latency round (r12: 2, r10: 3.5). Degrees via one int4.
// (2) X-operand MFMA pass moved BEFORE __syncthreads (global-only operands) ->
//     waves that finish gathering early do half their MFMA work while stragglers
//     gather, shrinking barrier idle.
// Occupancy fixed at r10's 12 waves/CU (r11: more waves -> L2 contention, BW drops;
// r8/r9: tighter launch_bounds -> scratch spill). VGPR ~105 under the (256,4)=128 cap.

template <bool FUSEFC>
__global__ __launch_bounds__(256, 4)
void fused_layer(const unsigned short* __restrict__ feat,
                 const int* __restrict__ cursor, const unsigned short* __restrict__ eidx_pad,
                 const unsigned short* __restrict__ zrow,
                 const unsigned short* __restrict__ Pl, const unsigned short* __restrict__ Pr,
                 const float* __restrict__ bias,
                 const unsigned short* __restrict__ Pfc, const float* __restrict__ bfc,
                 unsigned short* __restrict__ outb, float* __restrict__ outf, int n) {
    __shared__ __align__(16) unsigned short As[64][136];

    int tid = threadIdx.x;
    int row0 = blockIdx.x * 64;

    // gather-aggregate -> As: group g (16 lanes) handles nodes g*4..g*4+3
    {
        int g = tid >> 4;
        int l = tid & 15;
        int nbase = row0 + g * 4;
        // 4 degrees in one 16B load (nbase is 4-aligned; OOB lanes masked below)
        int4 dv = *(const int4*)(cursor + nbase);
        const unsigned short* rbase = eidx_pad + (size_t)nbase * PAD;
        // prime the id pipeline with node 0's ids
        uint4 ia = *(const uint4*)(rbase);
        uint4 ib = *(const uint4*)(rbase + 8);
#pragma unroll
        for (int nn = 0; nn < 4; ++nn) {
            int r = g * 4 + nn;
            int node = nbase + nn;
            uint4 ca = ia, cb = ib;
            if (nn < 3) {   // prefetch next node's ids while this node's gathers run
                ia = *(const uint4*)(rbase + (nn + 1) * PAD);
                ib = *(const uint4*)(rbase + (nn + 1) * PAD + 8);
            }
            int deg = 0;
            if (node < n) deg = ((const int*)&dv)[nn];
            float di = 1.0f / (float)(deg > 1 ? deg : 1);
            float acc[8] = {0.f, 0.f, 0.f, 0.f, 0.f, 0.f, 0.f, 0.f};
            {
                int id[16];
                id[0] = ca.x & 0xffff;  id[1] = ca.x >> 16;
                id[2] = ca.y & 0xffff;  id[3] = ca.y >> 16;
                id[4] = ca.z & 0xffff;  id[5] = ca.z >> 16;
                id[6] = ca.w & 0xffff;  id[7] = ca.w >> 16;
                id[8] = cb.x & 0xffff;  id[9] = cb.x >> 16;
                id[10] = cb.y & 0xffff; id[11] = cb.y >> 16;
                id[12] = cb.z & 0xffff; id[13] = cb.z >> 16;
                id[14] = cb.w & 0xffff; id[15] = cb.w >> 16;
                uint4 v[16];
#pragma unroll
                for (int k = 0; k < 16; ++k) {
                    const unsigned short* sp = (k < deg) ? (feat + (size_t)id[k] * D) : zrow;
                    v[k] = *(const uint4*)(sp + l * 8);
                }
#pragma unroll
                for (int k = 0; k < 16; ++k) {
                    acc[0] += bflo(v[k].x); acc[1] += bfhi(v[k].x);
                    acc[2] += bflo(v[k].y); acc[3] += bfhi(v[k].y);
                    acc[4] += bflo(v[k].z); acc[5] += bfhi(v[k].z);
                    acc[6] += bflo(v[k].w); acc[7] += bfhi(v[k].w);
                }
                // tail: predicated batches of 8 (P(deg>16) ~ 0.47)
                const unsigned short* rowp = rbase + nn * PAD;
                int p = 16;
                while (p < deg) {
                    uint4 iv = *(const uint4*)(rowp + p);
                    int jd[8];
                    jd[0] = iv.x & 0xffff; jd[1] = iv.x >> 16;
                    jd[2] = iv.y & 0xffff; jd[3] = iv.y >> 16;
                    jd[4] = iv.z & 0xffff; jd[5] = iv.z >> 16;
                    jd[6] = iv.w & 0xffff; jd[7] = iv.w >> 16;
                    uint4 w[8];
#pragma unroll
                    for (int k = 0; k < 8; ++k) {
                        const unsigned short* sp = (p + k < deg) ? (feat + (size_t)jd[k] * D) : zrow;
                        w[k] = *(const uint4*)(sp + l * 8);
                    }
#pragma unroll
                    for (int k = 0; k < 8; ++k) {
                        acc[0] += bflo(w[k].x); acc[1] += bfhi(w[k].x);
                        acc[2] += bflo(w[k].y); acc[3] += bfhi(w[k].y);
                        acc[4] += bflo(w[k].z); acc[5] += bfhi(w[k].z);
                        acc[6] += bflo(w[k].w); acc[7] += bfhi(w[k].w);
                    }
                    p += 8;
                }
            }
            unsigned int w0 = f2bf(acc[0] * di) | ((unsigned int)f2bf(acc[1] * di) << 16);
            unsigned int w1 = f2bf(acc[2] * di) | ((unsigned int)f2bf(acc[3] * di) << 16);
            unsigned int w2 = f2bf(acc[4] * di) | ((unsigned int)f2bf(acc[5] * di) << 16);
            unsigned int w3 = f2bf(acc[6] * di) | ((unsigned int)f2bf(acc[7] * di) << 16);
            *(uint4*)&As[r][l * 8] = make_uint4(w0, w1, w2, w3);
        }
    }

    int wave = tid >> 6;
    int lane = tid & 63;
    int m16 = lane & 15;
    int quad = lane >> 4;
    int rt0 = (wave & 1) * 32;
    int ctb = (wave >> 1) * 4;

    float4v acc[2][4];
#pragma unroll
    for (int t = 0; t < 2; ++t)
#pragma unroll
        for (int c = 0; c < 4; ++c) acc[t][c] = (float4v){0.f, 0.f, 0.f, 0.f};

    // X-operand pass FIRST (global-only: overlaps other waves' gather tails; no LDS dep)
#pragma unroll
    for (int ks = 0; ks < 4; ++ks) {
        short8 xf[2];
#pragma unroll
        for (int t = 0; t < 2; ++t) {
            int row = row0 + rt0 + t * 16 + m16;
            short8 z = {0, 0, 0, 0, 0, 0, 0, 0};
            xf[t] = (row < n) ? *(const short8*)(feat + (size_t)row * D + ks * 32 + quad * 8) : z;
        }
#pragma unroll
        for (int c = 0; c < 4; ++c) {
            short8 bf = *(const short8*)(Pr + ((size_t)((ks * 8 + ctb + c) * 64 + lane)) * 8);
#pragma unroll
            for (int t = 0; t < 2; ++t)
                acc[t][c] = __builtin_amdgcn_mfma_f32_16x16x32_bf16(xf[t], bf, acc[t][c], 0, 0, 0);
        }
    }

    __syncthreads();

    // A-operand pass (aggregated, from LDS)
#pragma unroll
    for (int ks = 0; ks < 4; ++ks) {
        short8 af[2];
#pragma unroll
        for (int t = 0; t < 2; ++t)
            af[t] = *(const short8*)&As[rt0 + t * 16 + m16][ks * 32 + quad * 8];
#pragma unroll
        for (int c = 0; c < 4; ++c) {
            short8 bf = *(const short8*)(Pl + ((size_t)((ks * 8 + ctb + c) * 64 + lane)) * 8);
#pragma unroll
            for (int t = 0; t < 2; ++t)
                acc[t][c] = __builtin_amdgcn_mfma_f32_16x16x32_bf16(af[t], bf, acc[t][c], 0, 0, 0);
        }
    }

    if (!FUSEFC) {
#pragma unroll
        for (int t = 0; t < 2; ++t) {
#pragma unroll
            for (int c = 0; c < 4; ++c) {
                int col = (ctb + c) * 16 + m16;
                float bv = bias[col];
#pragma unroll
                for (int i = 0; i < 4; ++i) {
                    int row = row0 + rt0 + t * 16 + quad * 4 + i;
                    if (row < n)
                        outb[(size_t)row * D + col] = f2bf(fmaxf(acc[t][c][i] + bv, 0.f));
                }
            }
        }
    } else {
        __syncthreads();
#pragma unroll
        for (int t = 0; t < 2; ++t) {
#pragma unroll
            for (int c = 0; c < 4; ++c) {
                int col = (ctb + c) * 16 + m16;
                float bv = bias[col];
#pragma unroll
                for (int i = 0; i < 4; ++i) {
                    int row = rt0 + t * 16 + quad * 4 + i;
                    As[row][col] = f2bf(fmaxf(acc[t][c][i] + bv, 0.f));
                }
            }
        }
        __syncthreads();

        int ctbF = (wave >> 1) * 2;
        float4v acc2[2][2];
#pragma unroll
        for (int t = 0; t < 2; ++t)
#pragma unroll
            for (int c = 0; c < 2; ++c) acc2[t][c] = (float4v){0.f, 0.f, 0.f, 0.f};
#pragma unroll
        for (int ks = 0; ks < 4; ++ks) {
            short8 hf[2];
#pragma unroll
            for (int t = 0; t < 2; ++t)
                hf[t] = *(const short8*)&As[rt0 + t * 16 + m16][ks * 32 + quad * 8];
#pragma unroll
            for (int c = 0; c < 2; ++c) {
                short8 bf = *(const short8*)(Pfc + ((size_t)((ks * 4 + ctbF + c) * 64 + lane)) * 8);
#pragma unroll
                for (int t = 0; t < 2; ++t)
                    acc2[t][c] = __builtin_amdgcn_mfma_f32_16x16x32_bf16(hf[t], bf, acc2[t][c], 0, 0, 0);
            }
        }
#pragma unroll
        for (int t = 0; t < 2; ++t) {
#pragma unroll
            for (int c = 0; c < 2; ++c) {
                int col = (ctbF + c) * 16 + m16;
                float bv = bfc[col];
#pragma unroll
                for (int i = 0; i < 4; ++i) {
                    int row = row0 + rt0 + t * 16 + quad * 4 + i;
                    if (row < n)
                        outf[(size_t)row * DOUT + col] = acc2[t][c][i] + bv;
                }
            }
        }
    }
}

// ---------------- launch ----------------

extern "C" void kernel_launch(void* const* d_in, const int* in_sizes, int n_in,
                              void* d_out, int out_size, void* d_ws, size_t ws_size,
                              hipStream_t stream) {
    const float* x   = (const float*)d_in[0];
    const int*   ei  = (const int*)d_in[1];
    const float* Wl0 = (const float*)d_in[2];
    const float* Wr0 = (const float*)d_in[3];
    const float* b0  = (const float*)d_in[4];
    const float* Wl1 = (const float*)d_in[5];
    const float* Wr1 = (const float*)d_in[6];
    const float* b1  = (const float*)d_in[7];
    const float* Wfc = (const float*)d_in[8];
    const float* bfc = (const float*)d_in[9];
    float* out = (float*)d_out;

    const int* src = ei;
    const int* dst = ei + NE;

    char* p = (char*)d_ws;
    auto carve = [&](size_t bytes) {
        char* q = p;
        p += (bytes + 255) & ~(size_t)255;
        return q;
    };
    int*            cursor   = (int*)carve(NN * sizeof(int));
    int*            gcur     = (int*)carve(NBUCK * sizeof(int));
    unsigned short* zrow     = (unsigned short*)carve(256);
    unsigned int*   binned   = (unsigned int*)carve((size_t)NBUCK * CAP * 4);
    unsigned short* eidx_pad = (unsigned short*)carve((size_t)NN * PAD * 2);
    unsigned short* xb   = (unsigned short*)carve((size_t)NN * D * 2);
    unsigned short* h0b  = (unsigned short*)carve((size_t)NN * D * 2);
    unsigned short* Wl0p = (unsigned short*)carve(D * D * 2);
    unsigned short* Wr0p = (unsigned short*)carve(D * D * 2);
    unsigned short* Wl1p = (unsigned short*)carve(D * D * 2);
    unsigned short* Wr1p = (unsigned short*)carve(D * D * 2);
    unsigned short* Wfcp = (unsigned short*)carve(D * DOUT * 2);

    PrepArgs pa;
    pa.W[0] = Wl0; pa.W[1] = Wr0; pa.W[2] = Wl1; pa.W[3] = Wr1; pa.W[4] = Wfc;
    pa.P[0] = Wl0p; pa.P[1] = Wr0p; pa.P[2] = Wl1p; pa.P[3] = Wr1p; pa.P[4] = Wfcp;
    pa.gcur = gcur;
    pa.x = x; pa.xb = xb;
    pa.zrow = zrow;
    prep<<<256, 256, 0, stream>>>(pa);

    const int BINB = (NE + CHUNK - 1) / CHUNK;   // 196
    bin_edges<<<BINB, 256, 0, stream>>>(src, dst, gcur, binned, NE);
    scatter_bucket<<<NBUCK, 512, 0, stream>>>(binned, gcur, eidx_pad, cursor);

    const int GB = (NN + 63) / 64;   // 782

    // layer 0: h0 = relu(agg(xb)@Wl0 + xb@Wr0 + b0)
    fused_layer<false><<<GB, 256, 0, stream>>>(xb, cursor, eidx_pad, zrow, Wl0p, Wr0p, b0,
                                               nullptr, nullptr, h0b, nullptr, NN);
    // layer 1 + FC: out = (relu(agg(h0)@Wl1 + h0@Wr1 + b1)) @ Wfc + bfc
    fused_layer<true><<<GB, 256, 0, stream>>>(h0b, cursor, eidx_pad, zrow, Wl1p, Wr1p, b1,
                                              Wfcp, bfc, nullptr, out, NN);
}

// Round 14
// 183.577 us; speedup vs baseline: 1.1414x; 1.0184x over previous
//
#include <hip/hip_runtime.h>
#include <hip/hip_bf16.h>

#define NN 50000
#define NE 800000
#define D 128
#define DOUT 64
#define PAD 64      // slots per node; P(deg>=64) ~ 2e-18 for Poisson(16)
#define BSH 8       // nodes per bucket = 256
#define NBUCK 196   // ceil(50000/256)
#define CHUNK 4096  // edges per bin block
#define NBINB 196   // ceil(800000/4096)
#define SEGC 56     // per-(bucket,block) capacity: mean 20.9 + 7.7 sigma
#define N8 (NN * D / 8)

typedef __attribute__((ext_vector_type(8))) short short8;
typedef __attribute__((ext_vector_type(4))) float float4v;

// ---------------- bf16 helpers ----------------

__device__ inline unsigned short f2bf(float f) {
    union { float f; unsigned int i; } c; c.f = f;
    unsigned int u = c.i;
    return (unsigned short)((u + 0x7fffu + ((u >> 16) & 1u)) >> 16);  // RNE
}
__device__ inline float bflo(unsigned int u) {
    union { unsigned int i; float f; } c; c.i = u << 16; return c.f;
}
__device__ inline float bfhi(unsigned int u) {
    union { unsigned int i; float f; } c; c.i = u & 0xffff0000u; return c.f;
}

// ---------------- stage 1 (ONE launch): bin edges (blocks 0..195, NO atomics,
// deterministic [bucket][block][SEGC] layout) + cast x->bf16 + pack weights +
// zero zrow (blocks 196..451). prep and bin are fully independent.

struct Stage1Args {
    const int* src;
    const int* dst;
    unsigned int* binned;   // [NBUCK][NBINB][SEGC]
    int* cnts;              // [NBINB][NBUCK]
    const float* W[5];
    unsigned short* P[5];
    const float* x;
    unsigned short* xb;
    unsigned short* zrow;
};

__global__ void stage1(Stage1Args args) {
    int blk = blockIdx.x;
    int tid = threadIdx.x;
    if (blk < NBINB) {
        // ---- bin_edges block ----
        __shared__ int cnt[NBUCK];
        __shared__ int sh[256];
        __shared__ int lcur[NBUCK];
        __shared__ unsigned int buf[CHUNK];
        int base = blk * CHUNK;
        for (int b = tid; b < NBUCK; b += 256) cnt[b] = 0;
        __syncthreads();
        unsigned int rec[16];
#pragma unroll
        for (int i = 0; i < 16; ++i) {
            int ei = base + i * 256 + tid;
            rec[i] = 0xffffffffu;
            if (ei < NE) {
                unsigned int d = (unsigned int)args.dst[ei];
                unsigned int s = (unsigned int)args.src[ei];
                rec[i] = (d << 16) | s;
                atomicAdd(&cnt[d >> BSH], 1);   // LDS atomic
            }
        }
        __syncthreads();
        int v = (tid < NBUCK) ? cnt[tid] : 0;
        sh[tid] = v;
        __syncthreads();
        for (int off = 1; off < 256; off <<= 1) {
            int t = (tid >= off) ? sh[tid - off] : 0;
            __syncthreads();
            sh[tid] += t;
            __syncthreads();
        }
        if (tid < NBUCK) {
            lcur[tid] = sh[tid] - cnt[tid];
            args.cnts[blk * NBUCK + tid] = (cnt[tid] < SEGC) ? cnt[tid] : SEGC;
        }
        __syncthreads();
        int total = sh[255];
#pragma unroll
        for (int i = 0; i < 16; ++i) {
            if (rec[i] != 0xffffffffu) {
                int b = rec[i] >> 24;
                int pos = atomicAdd(&lcur[b], 1);
                buf[pos] = rec[i];
            }
        }
        __syncthreads();
        // copy out: bucket run q -> binned[q][blk][0..cnt)
        for (int j = tid; j < total; j += 256) {
            unsigned int r = buf[j];
            int q = r >> 24;
            int k = j - (sh[q] - cnt[q]);
            if (k < SEGC)
                args.binned[((size_t)q * NBINB + blk) * SEGC + k] = r;
        }
    } else {
        int b = blk - NBINB;
        if (b < 36) {
            int idx = b * 256 + tid;   // 0..9215
            const float* W;
            unsigned short* P;
            int COLS, local;
            if (idx < 4 * 2048) {
                int wsel = idx >> 11;
                W = args.W[wsel]; P = args.P[wsel]; COLS = 128; local = idx & 2047;
            } else {
                W = args.W[4]; P = args.P[4]; COLS = 64; local = idx - 4 * 2048;
            }
            int CT = COLS >> 4;
            int lane = local & 63;
            int fi = local >> 6;
            int ct = fi % CT;
            int kstep = fi / CT;
            int krow = kstep * 32 + (lane >> 4) * 8;
            int col = ct * 16 + (lane & 15);
            unsigned short v[8];
#pragma unroll
            for (int j = 0; j < 8; ++j) v[j] = f2bf(W[(size_t)(krow + j) * COLS + col]);
            unsigned int w0 = v[0] | ((unsigned int)v[1] << 16);
            unsigned int w1 = v[2] | ((unsigned int)v[3] << 16);
            unsigned int w2 = v[4] | ((unsigned int)v[5] << 16);
            unsigned int w3 = v[6] | ((unsigned int)v[7] << 16);
            *(uint4*)(P + (size_t)local * 8) = make_uint4(w0, w1, w2, w3);
            if (b == 0 && tid < 16)   // 16 x uint4 = 256B zero row
                *(uint4*)(args.zrow + (size_t)tid * 8) = make_uint4(0, 0, 0, 0);
        } else {
            int stride = (gridDim.x - NBINB - 36) * 256;
            for (int i = (b - 36) * 256 + tid; i < N8; i += stride) {
                const float4* p = (const float4*)args.x + (size_t)i * 2;
                float4 a = p[0], bb = p[1];
                unsigned int w0 = f2bf(a.x) | ((unsigned int)f2bf(a.y) << 16);
                unsigned int w1 = f2bf(a.z) | ((unsigned int)f2bf(a.w) << 16);
                unsigned int w2 = f2bf(bb.x) | ((unsigned int)f2bf(bb.y) << 16);
                unsigned int w3 = f2bf(bb.z) | ((unsigned int)f2bf(bb.w) << 16);
                *(uint4*)(args.xb + (size_t)i * 8) = make_uint4(w0, w1, w2, w3);
            }
        }
    }
}

// ---------------- stage 2: per-bucket scatter, LDS cursors, L2-local writes --------

__global__ void scatter_bucket(const unsigned int* __restrict__ binned, const int* __restrict__ cnts,
                               unsigned short* __restrict__ eidx_pad, int* __restrict__ cursor) {
    __shared__ int cur[256];
    __shared__ int segc[NBINB];
    int q = blockIdx.x;
    int tid = threadIdx.x;
    if (tid < 256) cur[tid] = 0;
    for (int s = tid; s < NBINB; s += 512) segc[s] = cnts[(size_t)s * NBUCK + q];
    __syncthreads();
    const unsigned int* bq = binned + (size_t)q * NBINB * SEGC;
    for (int idx = tid; idx < NBINB * SEGC; idx += 512) {
        int seg = idx / SEGC;
        int k = idx - seg * SEGC;
        if (k < segc[seg]) {
            unsigned int r = bq[(size_t)seg * SEGC + k];
            int dl = (r >> 16) & 255;
            int slot = atomicAdd(&cur[dl], 1);
            if (slot < PAD)
                eidx_pad[((size_t)((q << BSH) + dl)) * PAD + slot] = (unsigned short)(r & 0xffffu);
        }
    }
    __syncthreads();
    if (tid < 256) {
        int node = (q << BSH) + tid;
        if (node < NN) cursor[node] = (cur[tid] < PAD) ? cur[tid] : PAD;
    }
}

// ---------------- fused layer: agg-gather + dual MFMA GEMM [+ fused FC] ----------------
// FROZEN r13 config (64-node tile, 256 thr, (256,4), 782 blocks = 3/CU, 12 waves/CU):
// id prefetch across a group's 4 contiguous nodes; 16 predicated gathers in flight
// (invalid -> zrow); X-operand MFMA pass before the barrier (global-only operands).
// Session lessons: more waves -> L2 contention (r11); tighter launch_bounds -> spill
// (r8/r9); this shape + short latency chains is the measured optimum.

template <bool FUSEFC>
__global__ __launch_bounds__(256, 4)
void fused_layer(const unsigned short* __restrict__ feat,
                 const int* __restrict__ cursor, const unsigned short* __restrict__ eidx_pad,
                 const unsigned short* __restrict__ zrow,
                 const unsigned short* __restrict__ Pl, const unsigned short* __restrict__ Pr,
                 const float* __restrict__ bias,
                 const unsigned short* __restrict__ Pfc, const float* __restrict__ bfc,
                 unsigned short* __restrict__ outb, float* __restrict__ outf, int n) {
    __shared__ __align__(16) unsigned short As[64][136];

    int tid = threadIdx.x;
    int row0 = blockIdx.x * 64;

    {
        int g = tid >> 4;
        int l = tid & 15;
        int nbase = row0 + g * 4;
        int4 dv = *(const int4*)(cursor + nbase);
        const unsigned short* rbase = eidx_pad + (size_t)nbase * PAD;
        uint4 ia = *(const uint4*)(rbase);
        uint4 ib = *(const uint4*)(rbase + 8);
#pragma unroll
        for (int nn = 0; nn < 4; ++nn) {
            int r = g * 4 + nn;
            int node = nbase + nn;
            uint4 ca = ia, cb = ib;
            if (nn < 3) {
                ia = *(const uint4*)(rbase + (nn + 1) * PAD);
                ib = *(const uint4*)(rbase + (nn + 1) * PAD + 8);
            }
            int deg = 0;
            if (node < n) deg = ((const int*)&dv)[nn];
            float di = 1.0f / (float)(deg > 1 ? deg : 1);
            float acc[8] = {0.f, 0.f, 0.f, 0.f, 0.f, 0.f, 0.f, 0.f};
            {
                int id[16];
                id[0] = ca.x & 0xffff;  id[1] = ca.x >> 16;
                id[2] = ca.y & 0xffff;  id[3] = ca.y >> 16;
                id[4] = ca.z & 0xffff;  id[5] = ca.z >> 16;
                id[6] = ca.w & 0xffff;  id[7] = ca.w >> 16;
                id[8] = cb.x & 0xffff;  id[9] = cb.x >> 16;
                id[10] = cb.y & 0xffff; id[11] = cb.y >> 16;
                id[12] = cb.z & 0xffff; id[13] = cb.z >> 16;
                id[14] = cb.w & 0xffff; id[15] = cb.w >> 16;
                uint4 v[16];
#pragma unroll
                for (int k = 0; k < 16; ++k) {
                    const unsigned short* sp = (k < deg) ? (feat + (size_t)id[k] * D) : zrow;
                    v[k] = *(const uint4*)(sp + l * 8);
                }
#pragma unroll
                for (int k = 0; k < 16; ++k) {
                    acc[0] += bflo(v[k].x); acc[1] += bfhi(v[k].x);
                    acc[2] += bflo(v[k].y); acc[3] += bfhi(v[k].y);
                    acc[4] += bflo(v[k].z); acc[5] += bfhi(v[k].z);
                    acc[6] += bflo(v[k].w); acc[7] += bfhi(v[k].w);
                }
                const unsigned short* rowp = rbase + nn * PAD;
                int p = 16;
                while (p < deg) {
                    uint4 iv = *(const uint4*)(rowp + p);
                    int jd[8];
                    jd[0] = iv.x & 0xffff; jd[1] = iv.x >> 16;
                    jd[2] = iv.y & 0xffff; jd[3] = iv.y >> 16;
                    jd[4] = iv.z & 0xffff; jd[5] = iv.z >> 16;
                    jd[6] = iv.w & 0xffff; jd[7] = iv.w >> 16;
                    uint4 w[8];
#pragma unroll
                    for (int k = 0; k < 8; ++k) {
                        const unsigned short* sp = (p + k < deg) ? (feat + (size_t)jd[k] * D) : zrow;
                        w[k] = *(const uint4*)(sp + l * 8);
                    }
#pragma unroll
                    for (int k = 0; k < 8; ++k) {
                        acc[0] += bflo(w[k].x); acc[1] += bfhi(w[k].x);
                        acc[2] += bflo(w[k].y); acc[3] += bfhi(w[k].y);
                        acc[4] += bflo(w[k].z); acc[5] += bfhi(w[k].z);
                        acc[6] += bflo(w[k].w); acc[7] += bfhi(w[k].w);
                    }
                    p += 8;
                }
            }
            unsigned int w0 = f2bf(acc[0] * di) | ((unsigned int)f2bf(acc[1] * di) << 16);
            unsigned int w1 = f2bf(acc[2] * di) | ((unsigned int)f2bf(acc[3] * di) << 16);
            unsigned int w2 = f2bf(acc[4] * di) | ((unsigned int)f2bf(acc[5] * di) << 16);
            unsigned int w3 = f2bf(acc[6] * di) | ((unsigned int)f2bf(acc[7] * di) << 16);
            *(uint4*)&As[r][l * 8] = make_uint4(w0, w1, w2, w3);
        }
    }

    int wave = tid >> 6;
    int lane = tid & 63;
    int m16 = lane & 15;
    int quad = lane >> 4;
    int rt0 = (wave & 1) * 32;
    int ctb = (wave >> 1) * 4;

    float4v acc[2][4];
#pragma unroll
    for (int t = 0; t < 2; ++t)
#pragma unroll
        for (int c = 0; c < 4; ++c) acc[t][c] = (float4v){0.f, 0.f, 0.f, 0.f};

    // X-operand pass FIRST (global-only: overlaps other waves' gather tails)
#pragma unroll
    for (int ks = 0; ks < 4; ++ks) {
        short8 xf[2];
#pragma unroll
        for (int t = 0; t < 2; ++t) {
            int row = row0 + rt0 + t * 16 + m16;
            short8 z = {0, 0, 0, 0, 0, 0, 0, 0};
            xf[t] = (row < n) ? *(const short8*)(feat + (size_t)row * D + ks * 32 + quad * 8) : z;
        }
#pragma unroll
        for (int c = 0; c < 4; ++c) {
            short8 bf = *(const short8*)(Pr + ((size_t)((ks * 8 + ctb + c) * 64 + lane)) * 8);
#pragma unroll
            for (int t = 0; t < 2; ++t)
                acc[t][c] = __builtin_amdgcn_mfma_f32_16x16x32_bf16(xf[t], bf, acc[t][c], 0, 0, 0);
        }
    }

    __syncthreads();

    // A-operand pass (aggregated, from LDS)
#pragma unroll
    for (int ks = 0; ks < 4; ++ks) {
        short8 af[2];
#pragma unroll
        for (int t = 0; t < 2; ++t)
            af[t] = *(const short8*)&As[rt0 + t * 16 + m16][ks * 32 + quad * 8];
#pragma unroll
        for (int c = 0; c < 4; ++c) {
            short8 bf = *(const short8*)(Pl + ((size_t)((ks * 8 + ctb + c) * 64 + lane)) * 8);
#pragma unroll
            for (int t = 0; t < 2; ++t)
                acc[t][c] = __builtin_amdgcn_mfma_f32_16x16x32_bf16(af[t], bf, acc[t][c], 0, 0, 0);
        }
    }

    if (!FUSEFC) {
#pragma unroll
        for (int t = 0; t < 2; ++t) {
#pragma unroll
            for (int c = 0; c < 4; ++c) {
                int col = (ctb + c) * 16 + m16;
                float bv = bias[col];
#pragma unroll
                for (int i = 0; i < 4; ++i) {
                    int row = row0 + rt0 + t * 16 + quad * 4 + i;
                    if (row < n)
                        outb[(size_t)row * D + col] = f2bf(fmaxf(acc[t][c][i] + bv, 0.f));
                }
            }
        }
    } else {
        __syncthreads();
#pragma unroll
        for (int t = 0; t < 2; ++t) {
#pragma unroll
            for (int c = 0; c < 4; ++c) {
                int col = (ctb + c) * 16 + m16;
                float bv = bias[col];
#pragma unroll
                for (int i = 0; i < 4; ++i) {
                    int row = rt0 + t * 16 + quad * 4 + i;
                    As[row][col] = f2bf(fmaxf(acc[t][c][i] + bv, 0.f));
                }
            }
        }
        __syncthreads();

        int ctbF = (wave >> 1) * 2;
        float4v acc2[2][2];
#pragma unroll
        for (int t = 0; t < 2; ++t)
#pragma unroll
            for (int c = 0; c < 2; ++c) acc2[t][c] = (float4v){0.f, 0.f, 0.f, 0.f};
#pragma unroll
        for (int ks = 0; ks < 4; ++ks) {
            short8 hf[2];
#pragma unroll
            for (int t = 0; t < 2; ++t)
                hf[t] = *(const short8*)&As[rt0 + t * 16 + m16][ks * 32 + quad * 8];
#pragma unroll
            for (int c = 0; c < 2; ++c) {
                short8 bf = *(const short8*)(Pfc + ((size_t)((ks * 4 + ctbF + c) * 64 + lane)) * 8);
#pragma unroll
                for (int t = 0; t < 2; ++t)
                    acc2[t][c] = __builtin_amdgcn_mfma_f32_16x16x32_bf16(hf[t], bf, acc2[t][c], 0, 0, 0);
            }
        }
#pragma unroll
        for (int t = 0; t < 2; ++t) {
#pragma unroll
            for (int c = 0; c < 2; ++c) {
                int col = (ctbF + c) * 16 + m16;
                float bv = bfc[col];
#pragma unroll
                for (int i = 0; i < 4; ++i) {
                    int row = row0 + rt0 + t * 16 + quad * 4 + i;
                    if (row < n)
                        outf[(size_t)row * DOUT + col] = acc2[t][c][i] + bv;
                }
            }
        }
    }
}

// ---------------- launch ----------------

extern "C" void kernel_launch(void* const* d_in, const int* in_sizes, int n_in,
                              void* d_out, int out_size, void* d_ws, size_t ws_size,
                              hipStream_t stream) {
    const float* x   = (const float*)d_in[0];
    const int*   ei  = (const int*)d_in[1];
    const float* Wl0 = (const float*)d_in[2];
    const float* Wr0 = (const float*)d_in[3];
    const float* b0  = (const float*)d_in[4];
    const float* Wl1 = (const float*)d_in[5];
    const float* Wr1 = (const float*)d_in[6];
    const float* b1  = (const float*)d_in[7];
    const float* Wfc = (const float*)d_in[8];
    const float* bfc = (const float*)d_in[9];
    float* out = (float*)d_out;

    const int* src = ei;
    const int* dst = ei + NE;

    char* p = (char*)d_ws;
    auto carve = [&](size_t bytes) {
        char* q = p;
        p += (bytes + 255) & ~(size_t)255;
        return q;
    };
    int*            cursor   = (int*)carve(NN * sizeof(int));
    int*            cnts     = (int*)carve((size_t)NBINB * NBUCK * sizeof(int));
    unsigned short* zrow     = (unsigned short*)carve(256);
    unsigned int*   binned   = (unsigned int*)carve((size_t)NBUCK * NBINB * SEGC * 4);
    unsigned short* eidx_pad = (unsigned short*)carve((size_t)NN * PAD * 2);
    unsigned short* xb   = (unsigned short*)carve((size_t)NN * D * 2);
    unsigned short* h0b  = (unsigned short*)carve((size_t)NN * D * 2);
    unsigned short* Wl0p = (unsigned short*)carve(D * D * 2);
    unsigned short* Wr0p = (unsigned short*)carve(D * D * 2);
    unsigned short* Wl1p = (unsigned short*)carve(D * D * 2);
    unsigned short* Wr1p = (unsigned short*)carve(D * D * 2);
    unsigned short* Wfcp = (unsigned short*)carve(D * DOUT * 2);

    Stage1Args sa;
    sa.src = src; sa.dst = dst;
    sa.binned = binned; sa.cnts = cnts;
    sa.W[0] = Wl0; sa.W[1] = Wr0; sa.W[2] = Wl1; sa.W[3] = Wr1; sa.W[4] = Wfc;
    sa.P[0] = Wl0p; sa.P[1] = Wr0p; sa.P[2] = Wl1p; sa.P[3] = Wr1p; sa.P[4] = Wfcp;
    sa.x = x; sa.xb = xb; sa.zrow = zrow;
    stage1<<<NBINB + 256, 256, 0, stream>>>(sa);   // bin (196) + pack (36) + cast (220)

    scatter_bucket<<<NBUCK, 512, 0, stream>>>(binned, cnts, eidx_pad, cursor);

    const int GB = (NN + 63) / 64;   // 782

    // layer 0: h0 = relu(agg(xb)@Wl0 + xb@Wr0 + b0)
    fused_layer<false><<<GB, 256, 0, stream>>>(xb, cursor, eidx_pad, zrow, Wl0p, Wr0p, b0,
                                               nullptr, nullptr, h0b, nullptr, NN);
    // layer 1 + FC: out = (relu(agg(h0)@Wl1 + h0@Wr1 + b1)) @ Wfc + bfc
    fused_layer<true><<<GB, 256, 0, stream>>>(h0b, cursor, eidx_pad, zrow, Wl1p, Wr1p, b1,
                                              Wfcp, bfc, nullptr, out, NN);
}